// Round 4
// baseline (132.423 us; speedup 1.0000x reference)
//
#include <hip/hip_runtime.h>
#include <hip/hip_bf16.h>

namespace {

constexpr int MM = 64;
constexpr int KK = 4096;
constexpr int NN = 11008;
constexpr int NZROW = NN / 8;        // 1376
constexpr int WB = 32;               // cols per block (all 4 waves share them)
constexpr int NWAVE = 4;             // waves per block, K split across waves
constexpr int KSEG = KK / NWAVE;     // 1024 k per wave
constexpr int BK = 32;               // k per chunk (one MFMA K)
constexpr int NCH = KSEG / BK;       // 32 chunks per wave
constexpr int NG = KSEG / 128;       // 8 scale-groups per wave
constexpr int NBLK = NN / WB;        // 344 blocks, single dispatch
constexpr int RST = 33;              // LDS row stride in floats (+1 pad)

typedef float f32x4 __attribute__((ext_vector_type(4)));
typedef short s16x8 __attribute__((ext_vector_type(8)));
typedef int   i32x4 __attribute__((ext_vector_type(4)));

__device__ __forceinline__ int pack_bf16(float a, float b) {
  union { __hip_bfloat162 h; int i; } u;
  u.h.x = __float2bfloat16(a);
  u.h.y = __float2bfloat16(b);
  return u.i;
}

// R9: single self-contained dispatch. K is split across the block's 4
// waves (wave w owns k in [w*1024, w*1024+1024) for the block's 32 cols);
// partials are combined through a 33-KB LDS tile, bias added, stored.
// No workspace, no reduce/prep/xcvt kernels, no cross-block combine.
// Inner loop = R8's register-direct B (one qweight dword = one MFMA
// B-fragment; exact 2^23 dequant, single rounding -> absmax unchanged),
// A converted in-loop from fp32 x (1 MB, L2-resident, reused 344x).
__global__ __launch_bounds__(256, 4) void gptq_gemm_kernel(
    const float* __restrict__ x, const int* __restrict__ qw,
    const int* __restrict__ qz, const float* __restrict__ scales,
    const float* __restrict__ bias, float* __restrict__ out)
{
  __shared__ float red[NWAVE * MM * RST];   // 4*64*33*4 = 33.8 KB

  const int tid  = threadIdx.x;
  const int wave = tid >> 6;
  const int lane = tid & 63;
  const int c    = lane & 15;
  const int quad = lane >> 4;

  const int n0     = blockIdx.x * WB;
  const int kbase0 = wave * KSEG;
  const int grp0   = kbase0 >> 7;          // = wave * 8

  const int ncol = n0 + c;                 // t=0 col; t=1 is ncol+16

  // B: qw row (kbase0/8 + quad), col ncol; chunk i advances 4 qw-rows
  const int* qwb = qw + ((size_t)(kbase0 >> 3) + quad) * NN + ncol;
  // A: row (r*16+c), k = kbase0 + i*32 + quad*8 (fp32, converted in-loop)
  const float* xab = x + (size_t)c * KK + kbase0 + quad * 8;

  f32x4 acc[8];   // acc[r*2+t]
  #pragma unroll
  for (int t = 0; t < 8; ++t) acc[t] = {0.f, 0.f, 0.f, 0.f};

  int   pB0[4], pB1[4];  // qweight ring, depth-3 (cold HBM stream)
  float pS0[2], pS1[2];  // scales, next-group prefetch
  int   pZ0[2], pZ1[2];  // qzeros
  float s0, s1, C0, C1;  // current-group dequant constants

  auto pfB = [&](int i) {
    const int* qp = qwb + (size_t)i * 4 * NN;
    pB0[i & 3] = qp[0];
    pB1[i & 3] = qp[16];
  };
  auto pfS = [&](int g) {
    const int sl = g & 1;
    const float* sp = scales + (size_t)(grp0 + g) * NN + ncol;
    pS0[sl] = sp[0];
    pS1[sl] = sp[16];
    const int* zp = qz + (size_t)(grp0 + g) * NZROW + (ncol >> 3);
    pZ0[sl] = zp[0];
    pZ1[sl] = zp[2];   // (ncol+16)>>3 == (ncol>>3)+2
  };
  auto setSC = [&](int g) {
    const int sl = g & 1;
    const int sh = (ncol & 7) * 4;       // same nibble for ncol and ncol+16
    s0 = pS0[sl];
    s1 = pS1[sl];
    C0 = __int_as_float(0x4B000000 + ((pZ0[sl] >> sh) & 15) + 1);
    C1 = __int_as_float(0x4B000000 + ((pZ1[sl] >> sh) & 15) + 1);
  };
  auto dq8 = [&](int v, float s, float C) -> i32x4 {
    i32x4 p;
    p.x = pack_bf16(s * (__int_as_float(((v      ) & 15) | 0x4B000000) - C),
                    s * (__int_as_float(((v >>  4) & 15) | 0x4B000000) - C));
    p.y = pack_bf16(s * (__int_as_float(((v >>  8) & 15) | 0x4B000000) - C),
                    s * (__int_as_float(((v >> 12) & 15) | 0x4B000000) - C));
    p.z = pack_bf16(s * (__int_as_float(((v >> 16) & 15) | 0x4B000000) - C),
                    s * (__int_as_float(((v >> 20) & 15) | 0x4B000000) - C));
    p.w = pack_bf16(s * (__int_as_float(((v >> 24) & 15) | 0x4B000000) - C),
                    s * (__int_as_float(((v >> 28) & 15) | 0x4B000000) - C));
    return p;
  };
  auto ldA = [&](int i, int r) -> s16x8 {
    const float* xa = xab + (size_t)r * 16 * KK + i * BK;
    const f32x4 a0 = *(const f32x4*)xa;
    const f32x4 a1 = *(const f32x4*)(xa + 4);
    union { i32x4 i4; s16x8 s8; } ua;
    ua.i4.x = pack_bf16(a0.x, a0.y);
    ua.i4.y = pack_bf16(a0.z, a0.w);
    ua.i4.z = pack_bf16(a1.x, a1.y);
    ua.i4.w = pack_bf16(a1.z, a1.w);
    return ua.s8;
  };

  // ---- prologue ----
  pfS(0);
  pfB(0); pfB(1); pfB(2);
  setSC(0);
  pfS(1);

  // full unroll: all ring indices (i&3, g&1) compile-time -> no scratch
  #pragma unroll
  for (int i = 0; i < NCH; ++i) {
    if (i + 3 < NCH) pfB(i + 3);               // deep qw prefetch

    union { i32x4 i4; s16x8 s8; } u0, u1;
    u0.i4 = dq8(pB0[i & 3], s0, C0);
    u1.i4 = dq8(pB1[i & 3], s1, C1);

    #pragma unroll
    for (int r = 0; r < 4; ++r) {
      const s16x8 af = ldA(i, r);
      acc[r * 2 + 0] = __builtin_amdgcn_mfma_f32_16x16x32_bf16(af, u0.s8, acc[r * 2 + 0], 0, 0, 0);
      acc[r * 2 + 1] = __builtin_amdgcn_mfma_f32_16x16x32_bf16(af, u1.s8, acc[r * 2 + 1], 0, 0, 0);
    }

    if ((i & 3) == 3) {
      const int g = i >> 2;
      if (g + 1 < NG) { setSC(g + 1); if (g + 2 < NG) pfS(g + 2); }
    }
  }

  // ---- combine 4 wave-partials through LDS, add bias, store ----
  // write: rows r*16+quad*4+j, cols c+t*16; stride 33 -> max 4-way bank alias
  float* rw = red + (size_t)(wave * MM) * RST;
  #pragma unroll
  for (int r = 0; r < 4; ++r) {
    #pragma unroll
    for (int t = 0; t < 2; ++t) {
      const f32x4 a = acc[r * 2 + t];
      float* p = rw + (r * 16 + quad * 4) * RST + c + t * 16;
      p[0]       = a.x;
      p[RST]     = a.y;
      p[2 * RST] = a.z;
      p[3 * RST] = a.w;
    }
  }
  __syncthreads();

  // each thread: 8 outputs (row = tid/4, cols col0..col0+7)
  const int row  = tid >> 2;
  const int col0 = (tid & 3) * 8;
  const f32x4 b0 = *(const f32x4*)(bias + n0 + col0);
  const f32x4 b1 = *(const f32x4*)(bias + n0 + col0 + 4);
  float sum[8] = {b0.x, b0.y, b0.z, b0.w, b1.x, b1.y, b1.z, b1.w};
  #pragma unroll
  for (int w = 0; w < NWAVE; ++w) {
    const float* rp = red + (size_t)(w * MM + row) * RST + col0;
    #pragma unroll
    for (int j = 0; j < 8; ++j) sum[j] += rp[j];
  }
  float* op = out + (size_t)row * NN + n0 + col0;
  f32x4 o0 = {sum[0], sum[1], sum[2], sum[3]};
  f32x4 o1 = {sum[4], sum[5], sum[6], sum[7]};
  *(f32x4*)op       = o0;
  *(f32x4*)(op + 4) = o1;
}

} // namespace

extern "C" void kernel_launch(void* const* d_in, const int* in_sizes, int n_in,
                              void* d_out, int out_size, void* d_ws, size_t ws_size,
                              hipStream_t stream) {
  const float* x      = (const float*)d_in[0];
  const int*   qw     = (const int*)d_in[1];
  const int*   qz     = (const int*)d_in[2];
  const float* scales = (const float*)d_in[3];
  const float* bias   = (const float*)d_in[4];
  float* out = (float*)d_out;
  (void)d_ws; (void)ws_size;  // workspace unused: single self-contained dispatch

  gptq_gemm_kernel<<<NBLK, 256, 0, stream>>>(x, qw, qz, scales, bias, out);
}